// Round 2
// baseline (900.184 us; speedup 1.0000x reference)
//
#include <hip/hip_runtime.h>

#define HID 128

typedef __attribute__((ext_vector_type(8))) short short8;
typedef __attribute__((ext_vector_type(4))) float f32x4;

__device__ __forceinline__ float bf2f(unsigned short u) {
  union { unsigned int u; float f; } c; c.u = ((unsigned int)u) << 16; return c.f;
}
__device__ __forceinline__ unsigned short f2bf(float f) {
  union { float f; unsigned int u; } c; c.f = f;
  unsigned int u = c.u;
  return (unsigned short)((u + 0x7FFFu + ((u >> 16) & 1u)) >> 16);  // RNE
}
__device__ __forceinline__ float loads(const void* p, size_t i, bool f32) {
  return f32 ? ((const float*)p)[i] : bf2f(((const unsigned short*)p)[i]);
}
// Load an MFMA A-fragment (8 contiguous k-elements at row*HID+k) as bf16x8.
__device__ __forceinline__ short8 load_a8(const void* base, size_t row, int k, bool f32) {
  if (!f32) return *(const short8*)((const unsigned short*)base + row * HID + k);
  const float* fp = (const float*)base + row * HID + k;
  f32x4 f0 = *(const f32x4*)fp;
  f32x4 f1 = *(const f32x4*)(fp + 4);
  short8 t;
  t[0] = (short)f2bf(f0[0]); t[1] = (short)f2bf(f0[1]);
  t[2] = (short)f2bf(f0[2]); t[3] = (short)f2bf(f0[3]);
  t[4] = (short)f2bf(f1[0]); t[5] = (short)f2bf(f1[1]);
  t[6] = (short)f2bf(f1[2]); t[7] = (short)f2bf(f1[3]);
  return t;
}

// ---------------------------------------------------------------------------
// Runtime dtype detection. flags[0]=1 if float arrays are fp32 (else bf16).
// flags[1]=1 if edge_index is int64 (else int32).
// fp32 read as ushorts: every low-half is uniform garbage -> ~40% implausible
// bf16 exponent fields. bf16 N(0,1) data: ~0% implausible.
// int64 read as int32: odd slots are all high-words == 0 (values < 2^31).
// ---------------------------------------------------------------------------
__global__ void detect_kernel(const void* __restrict__ x,
                              const int* __restrict__ eidx,
                              int* __restrict__ flags) {
  __shared__ int bad, oddnz;
  if (threadIdx.x == 0) { bad = 0; oddnz = 0; }
  __syncthreads();
  const unsigned short* xu = (const unsigned short*)x;
  int mybad = 0;
  for (int i = threadIdx.x; i < 4096; i += 256) {
    int ef = (xu[i] >> 7) & 0xFF;
    if (!(ef == 0 || (ef >= 90 && ef <= 140))) mybad++;
  }
  if (mybad) atomicAdd(&bad, mybad);
  int t = threadIdx.x;
  if (t < 128) {
    if (eidx[2 * t + 1] != 0) atomicAdd(&oddnz, 1);
  }
  __syncthreads();
  if (threadIdx.x == 0) {
    flags[0] = (bad > 409) ? 1 : 0;
    flags[1] = (oddnz == 0) ? 1 : 0;
  }
}

// Zero d_out (element width per dtype flag). Used only in small-ws mode.
__global__ void zero_out_kernel(unsigned int* __restrict__ out,
                                const int* __restrict__ flags, long long nelem) {
  bool f32 = flags[0] != 0;
  size_t words = (size_t)nelem * (f32 ? 2 : 1) / 2;  // nelem*4/4 : nelem*2/4
  for (size_t w = blockIdx.x * 256ull + threadIdx.x; w < words; w += (size_t)gridDim.x * 256ull)
    out[w] = 0u;
}

// ---------------------------------------------------------------------------
// Repack W[K x 128] into MFMA B-fragment order (bf16), dtype-flexible read:
// pack[((ks*8+ct)*64+lane)*8+j] = W[(ks*32+(lane>>4)*8+j)*128 + ct*16+(lane&15)]
// ---------------------------------------------------------------------------
__global__ void repack_all(const void* __restrict__ W1, const void* __restrict__ W2,
                           const void* __restrict__ U1, const void* __restrict__ U2,
                           unsigned short* __restrict__ P1, unsigned short* __restrict__ P2,
                           unsigned short* __restrict__ PU1, unsigned short* __restrict__ PU2,
                           const int* __restrict__ flags) {
  const bool f32 = flags[0] != 0;
  int idx = blockIdx.x * 256 + threadIdx.x;
  const int s1 = 384 * 128, s2 = s1 + 128 * 128, s3 = s2 + 256 * 128, s4 = s3 + 128 * 128;
  if (idx >= s4) return;
  const void* W; unsigned short* P; int off;
  if (idx < s1)      { W = W1; P = P1;  off = idx; }
  else if (idx < s2) { W = W2; P = P2;  off = idx - s1; }
  else if (idx < s3) { W = U1; P = PU1; off = idx - s2; }
  else               { W = U2; P = PU2; off = idx - s3; }
  int j = off & 7, lane = (off >> 3) & 63, ct = (off >> 9) & 7, ks = off >> 12;
  int k = ks * 32 + ((lane >> 4) << 3) + j;
  int n = ct * 16 + (lane & 15);
  P[off] = f2bf(loads(W, (size_t)k * 128 + n, f32));
}

// ---------------------------------------------------------------------------
// Edge kernel: msg = MLP(concat(x[src],x[dst],eattr)), scatter-add by dst.
// ---------------------------------------------------------------------------
__global__ __launch_bounds__(256) void edge_kernel(
    const void* __restrict__ x, const int* __restrict__ eidx,
    const void* __restrict__ eattr,
    const unsigned short* __restrict__ P1, const void* __restrict__ b1,
    const unsigned short* __restrict__ P2, const void* __restrict__ b2,
    float* __restrict__ aggf, void* __restrict__ out,
    const int* __restrict__ flags, int E, int N, int small_mode) {
  __shared__ unsigned short hs[64][136];
  const bool f32 = flags[0] != 0;
  const bool i64 = flags[1] != 0;
  const int tid  = threadIdx.x;
  const int lane = tid & 63;
  const int wid  = tid >> 6;
  const int l15  = lane & 15;
  const int quad = lane >> 4;
  const int base = blockIdx.x * 64;

  int me = base + wid * 16 + l15;
  if (me >= E) me = E - 1;
  int src = i64 ? eidx[2 * me] : eidx[me];
  int dsm = i64 ? eidx[2 * (E + me)] : eidx[E + me];
  src = min(max(src, 0), N - 1);
  dsm = min(max(dsm, 0), N - 1);

  f32x4 zero = {0.f, 0.f, 0.f, 0.f};
  f32x4 acc[8];
#pragma unroll
  for (int ct = 0; ct < 8; ct++) acc[ct] = zero;

  // GEMM1: [64 x 384] @ [384 x 128]
#pragma unroll
  for (int ks = 0; ks < 12; ks++) {
    const int k0 = ks * 32;
    short8 a;
    if (k0 < 128)      a = load_a8(x,     (size_t)src, k0 + quad * 8, f32);
    else if (k0 < 256) a = load_a8(x,     (size_t)dsm, (k0 - 128) + quad * 8, f32);
    else               a = load_a8(eattr, (size_t)me,  (k0 - 256) + quad * 8, f32);
    const unsigned short* wp = P1 + ((size_t)(ks * 8) * 64 + lane) * 8;
#pragma unroll
    for (int ct = 0; ct < 8; ct++) {
      short8 b = *(const short8*)(wp + ct * 512);
      acc[ct] = __builtin_amdgcn_mfma_f32_16x16x32_bf16(a, b, acc[ct], 0, 0, 0);
    }
  }

  // bias + ReLU, C-layout (row=quad*4+r, col=ct*16+l15) -> LDS bf16
#pragma unroll
  for (int ct = 0; ct < 8; ct++) {
    const int col = ct * 16 + l15;
    const float bv = loads(b1, col, f32);
#pragma unroll
    for (int r = 0; r < 4; r++) {
      float v = acc[ct][r] + bv;
      hs[wid * 16 + quad * 4 + r][col] = f2bf(fmaxf(v, 0.f));
    }
  }
  __syncthreads();

  // GEMM2: [64 x 128] @ [128 x 128]
  f32x4 acc2[8];
#pragma unroll
  for (int ct = 0; ct < 8; ct++) acc2[ct] = zero;
#pragma unroll
  for (int ks = 0; ks < 4; ks++) {
    short8 a = *(const short8*)&hs[wid * 16 + l15][ks * 32 + quad * 8];
    const unsigned short* wp = P2 + ((size_t)(ks * 8) * 64 + lane) * 8;
#pragma unroll
    for (int ct = 0; ct < 8; ct++) {
      short8 b = *(const short8*)(wp + ct * 512);
      acc2[ct] = __builtin_amdgcn_mfma_f32_16x16x32_bf16(a, b, acc2[ct], 0, 0, 0);
    }
  }

  float b2v[8];
#pragma unroll
  for (int ct = 0; ct < 8; ct++) b2v[ct] = loads(b2, ct * 16 + l15, f32);

  if (!small_mode || f32) {
    // fp32 atomics into aggf (full mode) or d_out-as-fp32 (small mode, fp32 world)
    float* tgt = (!small_mode) ? aggf : (float*)out;
#pragma unroll
    for (int r = 0; r < 4; r++) {
      const int e = base + wid * 16 + quad * 4 + r;
      if (e < E) {
        int d = i64 ? eidx[2 * (E + e)] : eidx[E + e];
        d = min(max(d, 0), N - 1);
        float* op = tgt + (size_t)d * HID + l15;
#pragma unroll
        for (int ct = 0; ct < 8; ct++) atomicAdd(op + ct * 16, acc2[ct][r] + b2v[ct]);
      }
    }
  } else {
    // small-ws + bf16 world: packed-bf16 CAS accumulate into d_out.
    // Stage messages to LDS (own rows only, no barrier needed before write).
#pragma unroll
    for (int ct = 0; ct < 8; ct++) {
      const int col = ct * 16 + l15;
#pragma unroll
      for (int r = 0; r < 4; r++)
        hs[wid * 16 + quad * 4 + r][col] = f2bf(acc2[ct][r] + b2v[ct]);
    }
    __syncthreads();
    const int row = tid >> 2;
    const int cg  = (tid & 3) * 32;
    const int e = base + row;
    if (e < E) {
      int d = i64 ? eidx[2 * (E + e)] : eidx[E + e];
      d = min(max(d, 0), N - 1);
      unsigned int* orow = (unsigned int*)out + ((size_t)d * HID >> 1);
#pragma unroll
      for (int p = 0; p < 16; p++) {
        const int col = cg + p * 2;
        const float lo = bf2f(hs[row][col]);
        const float hi = bf2f(hs[row][col + 1]);
        unsigned int* wp = orow + (col >> 1);
        unsigned int old = *wp, assumed;
        do {
          assumed = old;
          unsigned int nv = (unsigned int)f2bf(bf2f((unsigned short)(assumed & 0xFFFF)) + lo)
                          | ((unsigned int)f2bf(bf2f((unsigned short)(assumed >> 16)) + hi) << 16);
          old = atomicCAS(wp, assumed, nv);
        } while (old != assumed);
      }
    }
  }
}

// ---------------------------------------------------------------------------
// Node kernel: u = relu([x|agg]@U1+ub1); upd = u@U2+ub2; out = LN(x+upd)*g+b
// In small-ws mode agg lives in d_out; each wave reads ONLY its own 16 rows
// before overwriting them -> no cross-block hazard.
// ---------------------------------------------------------------------------
__global__ __launch_bounds__(256) void node_kernel(
    const void* __restrict__ x, const float* __restrict__ aggf,
    const unsigned short* __restrict__ PU1, const void* __restrict__ ub1,
    const unsigned short* __restrict__ PU2, const void* __restrict__ ub2,
    const void* __restrict__ gamma, const void* __restrict__ beta,
    void* __restrict__ out, const int* __restrict__ flags, int N, int small_mode) {
  __shared__ unsigned short hs[64][136];
  const bool f32 = flags[0] != 0;
  const int tid  = threadIdx.x;
  const int lane = tid & 63;
  const int wid  = tid >> 6;
  const int l15  = lane & 15;
  const int quad = lane >> 4;
  const int base = blockIdx.x * 64;

  int mn = base + wid * 16 + l15;
  if (mn >= N) mn = N - 1;

  const void* aggp = (!small_mode) ? (const void*)aggf : (const void*)out;
  const bool aggF32 = (!small_mode) ? true : f32;

  f32x4 zero = {0.f, 0.f, 0.f, 0.f};
  f32x4 acc[8];
#pragma unroll
  for (int ct = 0; ct < 8; ct++) acc[ct] = zero;

  // GEMM1: [64 x 256] @ [256 x 128]
#pragma unroll
  for (int ks = 0; ks < 8; ks++) {
    const int k0 = ks * 32;
    short8 a;
    if (k0 < 128) a = load_a8(x,    (size_t)mn, k0 + quad * 8, f32);
    else          a = load_a8(aggp, (size_t)mn, (k0 - 128) + quad * 8, aggF32);
    const unsigned short* wp = PU1 + ((size_t)(ks * 8) * 64 + lane) * 8;
#pragma unroll
    for (int ct = 0; ct < 8; ct++) {
      short8 b = *(const short8*)(wp + ct * 512);
      acc[ct] = __builtin_amdgcn_mfma_f32_16x16x32_bf16(a, b, acc[ct], 0, 0, 0);
    }
  }

#pragma unroll
  for (int ct = 0; ct < 8; ct++) {
    const int col = ct * 16 + l15;
    const float bv = loads(ub1, col, f32);
#pragma unroll
    for (int r = 0; r < 4; r++) {
      float v = acc[ct][r] + bv;
      hs[wid * 16 + quad * 4 + r][col] = f2bf(fmaxf(v, 0.f));
    }
  }
  __syncthreads();

  f32x4 acc2[8];
#pragma unroll
  for (int ct = 0; ct < 8; ct++) acc2[ct] = zero;
#pragma unroll
  for (int ks = 0; ks < 4; ks++) {
    short8 a = *(const short8*)&hs[wid * 16 + l15][ks * 32 + quad * 8];
    const unsigned short* wp = PU2 + ((size_t)(ks * 8) * 64 + lane) * 8;
#pragma unroll
    for (int ct = 0; ct < 8; ct++) {
      short8 b = *(const short8*)(wp + ct * 512);
      acc2[ct] = __builtin_amdgcn_mfma_f32_16x16x32_bf16(a, b, acc2[ct], 0, 0, 0);
    }
  }

  // Epilogue: v = x + upd; LayerNorm per row (row lives in one 16-lane group).
  float vals[8][4];
  float s1[4] = {0.f, 0.f, 0.f, 0.f};
  float s2[4] = {0.f, 0.f, 0.f, 0.f};
#pragma unroll
  for (int ct = 0; ct < 8; ct++) {
    const int col = ct * 16 + l15;
    const float bv = loads(ub2, col, f32);
#pragma unroll
    for (int r = 0; r < 4; r++) {
      int row = base + wid * 16 + quad * 4 + r;
      int rc = row < N ? row : 0;
      float v = acc2[ct][r] + bv + loads(x, (size_t)rc * HID + col, f32);
      vals[ct][r] = v;
      s1[r] += v;
      s2[r] += v * v;
    }
  }
#pragma unroll
  for (int off = 1; off < 16; off <<= 1) {
#pragma unroll
    for (int r = 0; r < 4; r++) {
      s1[r] += __shfl_xor(s1[r], off, 16);
      s2[r] += __shfl_xor(s2[r], off, 16);
    }
  }
#pragma unroll
  for (int r = 0; r < 4; r++) {
    const int row = base + wid * 16 + quad * 4 + r;
    if (row < N) {
      const float mean = s1[r] * (1.0f / 128.0f);
      const float var  = fmaxf(s2[r] * (1.0f / 128.0f) - mean * mean, 0.0f);
      const float rstd = rsqrtf(var + 1e-5f);
#pragma unroll
      for (int ct = 0; ct < 8; ct++) {
        const int col = ct * 16 + l15;
        float o = (vals[ct][r] - mean) * rstd * loads(gamma, col, f32) + loads(beta, col, f32);
        if (f32) ((float*)out)[(size_t)row * HID + col] = o;
        else     ((unsigned short*)out)[(size_t)row * HID + col] = f2bf(o);
      }
    }
  }
}

// ---------------------------------------------------------------------------
extern "C" void kernel_launch(void* const* d_in, const int* in_sizes, int n_in,
                              void* d_out, int out_size, void* d_ws, size_t ws_size,
                              hipStream_t stream) {
  (void)n_in;
  const void* x     = d_in[0];
  const int*  eidx  = (const int*)d_in[1];
  const void* eattr = d_in[2];
  const void* W1  = d_in[3];
  const void* b1  = d_in[4];
  const void* W2  = d_in[5];
  const void* b2  = d_in[6];
  const void* U1  = d_in[7];
  const void* ub1 = d_in[8];
  const void* U2  = d_in[9];
  const void* ub2 = d_in[10];
  const void* gam = d_in[11];
  const void* bet = d_in[12];

  const int N = in_sizes[0] / HID;
  const int E = in_sizes[2] / HID;

  char* ws = (char*)d_ws;
  int* flags = (int*)ws;                                         // 256 B
  unsigned short* P1  = (unsigned short*)(ws + 256);             // 98304 B
  unsigned short* P2  = (unsigned short*)(ws + 256 + 98304);     // 32768 B
  unsigned short* PU1 = (unsigned short*)(ws + 256 + 131072);    // 65536 B
  unsigned short* PU2 = (unsigned short*)(ws + 256 + 196608);    // 32768 B
  const size_t agg_off = 256 + 229376;                           // 229632, 256-aligned
  float* aggf = (float*)(ws + agg_off);
  const size_t need = agg_off + (size_t)N * HID * sizeof(float); // ~25.83 MB
  const int small_mode = (ws_size < need) ? 1 : 0;

  detect_kernel<<<1, 256, 0, stream>>>(x, eidx, flags);
  if (!small_mode) {
    hipMemsetAsync(aggf, 0, (size_t)N * HID * sizeof(float), stream);
  } else {
    zero_out_kernel<<<1024, 256, 0, stream>>>((unsigned int*)d_out, flags, (long long)out_size);
  }
  repack_all<<<448, 256, 0, stream>>>(W1, W2, U1, U2, P1, P2, PU1, PU2, flags);
  edge_kernel<<<(E + 63) / 64, 256, 0, stream>>>(x, eidx, eattr, P1, b1, P2, b2,
                                                 aggf, d_out, flags, E, N, small_mode);
  node_kernel<<<(N + 63) / 64, 256, 0, stream>>>(x, aggf, PU1, ub1, PU2, ub2,
                                                 gam, bet, d_out, flags, N, small_mode);
}